// Round 5
// baseline (117.378 us; speedup 1.0000x reference)
//
#include <hip/hip_runtime.h>
#include <hip/hip_bf16.h>

// EpiLinear: epinet (2080->512->32, z-contract) + prior ensemble (32x [1024->5->5->1], z-contract)
// B=2048, NZ=8, ND=32, STATE=HIDDEN=1024, EPI_HIDDEN=512. All inputs/outputs FP32.
//
//  - hx = [x|feature] @ Wep1[0:2048,:] shared across 8 z-samples -> GEMM [2048x2048]x[2048x672]
//    (prior layer-1 folded in as cols 512..671 of WT).
//  - GEMM: 128x128 tile, mfma 16x16x32 bf16, global_load_lds w=16, XOR LDS swizzle, split-K=8.
//    Slice-dependent N: slices 0-3 (k<1024) cover cols 0..767 (ny<6), slices 4-7 cols 0..511
//    (ny<4) since prior cols are zero there -> 640 blocks, -17% FLOPs.
//  - Gp partials stored BF16 (error ~0.003 << 0.82 threshold): halves write+read traffic.
//  - combine: 1024 blocks x 128 thr, 2 b's/block (16 (b,n) rows = one exact M=16 MFMA tile);
//    zW + layer-2 via MFMA with B-frags straight from global WzT/W2T; prior tail fp32 VALU.

typedef __hip_bfloat16 bf16;
typedef __attribute__((ext_vector_type(8))) short short8;   // 8 bf16 = 4 VGPRs (MFMA A/B frag)
typedef __attribute__((ext_vector_type(4))) float f32x4;    // MFMA C/D frag

#define NCOMB 768
#define A_BYTES   (2048u * 2048u * 2u)
#define WT_BYTES  (768u * 2048u * 2u)
#define WZT_BYTES (512u * 32u * 2u)
#define W2T_BYTES (32u * 512u * 2u)
#define GP_SSTR ((size_t)2048 * NCOMB)

__device__ __forceinline__ void gload_lds16(const bf16* g, bf16* l) {
    __builtin_amdgcn_global_load_lds(
        (const __attribute__((address_space(1))) void*)g,
        (__attribute__((address_space(3))) void*)l, 16, 0, 0);
}

__device__ __forceinline__ short f2bf_bits(float f) {
    bf16 h = __float2bfloat16(f);
    return *reinterpret_cast<short*>(&h);
}
__device__ __forceinline__ float bfu2f(unsigned short u) {
    return __uint_as_float(((unsigned int)u) << 16);
}

// ---------------------------------------------------------------------------
// merged prep: [0,4096) A; [4096,4352) WT transpose; [4352,5376) WT prior (k<1024 only);
//              [5376,5408) WzT; [5408,5440) W2T.
__global__ __launch_bounds__(256) void prep(const float* __restrict__ x,
                                            const float* __restrict__ feat,
                                            const float* __restrict__ Wep1,
                                            const float* __restrict__ Wep2,
                                            const float* __restrict__ Wp1,
                                            bf16* __restrict__ A,
                                            bf16* __restrict__ WT,
                                            bf16* __restrict__ WzT,
                                            bf16* __restrict__ W2T) {
    const int t = threadIdx.x;
    const int blk = blockIdx.x;
    if (blk < 4096) {
        // A[b][0:1024]=x[b], A[b][1024:2048]=feature[b]
        int idx = blk * 256 + t;
        int b = idx >> 9;
        int g = idx & 511;
        const float* src = (g < 256) ? (x + (size_t)b * 1024 + g * 4)
                                     : (feat + (size_t)b * 1024 + (g - 256) * 4);
        float4 v = *(const float4*)src;
        short4 p;
        p.x = f2bf_bits(v.x); p.y = f2bf_bits(v.y);
        p.z = f2bf_bits(v.z); p.w = f2bf_bits(v.w);
        *(short4*)(A + (size_t)b * 2048 + g * 4) = p;
    } else if (blk < 4352) {
        // 64x64 tiled transpose of Wep1[0:2048][0:512] -> WT[n][k]
        __shared__ short tile[64 * 66];
        int wb = blk - 4096;
        int kt = wb >> 3, nt = wb & 7;
        int k0 = kt * 64, n0 = nt * 64;
        int r = t >> 4, cq = t & 15;
#pragma unroll
        for (int i = 0; i < 4; ++i) {
            int rr = r + i * 16;
            float4 v = *(const float4*)(Wep1 + (size_t)(k0 + rr) * 512 + n0 + cq * 4);
            tile[(cq * 4 + 0) * 66 + rr] = f2bf_bits(v.x);
            tile[(cq * 4 + 1) * 66 + rr] = f2bf_bits(v.y);
            tile[(cq * 4 + 2) * 66 + rr] = f2bf_bits(v.z);
            tile[(cq * 4 + 3) * 66 + rr] = f2bf_bits(v.w);
        }
        __syncthreads();
#pragma unroll
        for (int i = 0; i < 2; ++i) {
            int ch = i * 256 + t;
            int nr = ch >> 3, kc = ch & 7;
            short8 s = *(const short8*)(tile + nr * 66 + kc * 8);
            *(short8*)(WT + (size_t)(n0 + nr) * 2048 + k0 + kc * 8) = s;
        }
    } else if (blk < 5376) {
        // prior cols 512..767, k<1024 only (k>=1024 never read: slices 4-7 stop at col 512)
        int local = (blk - 4352) * 256 + t;       // 262144: n in [512,768) x k in [0,1024)
        int n = 512 + (local >> 10);
        int k = local & 1023;
        float v = 0.f;
        if (n < 672) {
            int q = n - 512;
            int e = q / 5, h = q - e * 5;
            v = Wp1[(size_t)e * 5120 + k * 5 + h];
        }
        WT[(size_t)n * 2048 + k] = __float2bfloat16(v);
    } else if (blk < 5408) {
        // WzT[c][k] = Wep1[2048+k][c]
        int local = (blk - 5376) * 256 + t;
#pragma unroll
        for (int i = 0; i < 2; ++i) {
            int e = i * 8192 + local;
            int c = e >> 5, k = e & 31;
            WzT[e] = __float2bfloat16(Wep1[(size_t)(2048 + k) * 512 + c]);
        }
    } else {
        // W2T[j][c] = Wep2[c][j]
        int local = (blk - 5408) * 256 + t;
#pragma unroll
        for (int i = 0; i < 2; ++i) {
            int e = i * 8192 + local;
            int j = e >> 9, c = e & 511;
            W2T[e] = __float2bfloat16(Wep2[(size_t)c * 32 + j]);
        }
    }
}

// ---------------------------------------------------------------------------
// Gp[s][b][c] (bf16) = sum_{k in [s*256,(s+1)*256)} A[b][k] * WT[c][k].
// grid (16, 40): y<24 -> s=y/6, ny=y%6 (slices 0-3); y>=24 -> s=4+(y-24)/4, ny=(y-24)%4.
__global__ __launch_bounds__(256) void gemm_split(const bf16* __restrict__ A,
                                                  const bf16* __restrict__ WT,
                                                  bf16* __restrict__ Gp) {
    __shared__ bf16 As[128 * 64];
    __shared__ bf16 Bs[128 * 64];
    const int t    = threadIdx.x;
    const int lane = t & 63;
    const int wv   = t >> 6;
    const int y = blockIdx.y;
    int s, ny;
    if (y < 24) { s = y / 6; ny = y - s * 6; }
    else        { int q = y - 24; s = 4 + (q >> 2); ny = q & 3; }
    const int m0 = blockIdx.x * 128;          // m-tile on x: same-m blocks cluster per XCD
    const int n0 = ny * 128;
    const int kbase = s * 256;
    const int lm = lane & 15;
    const int lq = lane >> 4;
    const int wm = (wv & 1) * 64;
    const int wn = (wv >> 1) * 64;
    f32x4 acc[4][4] = {};

    for (int k0 = 0; k0 < 256; k0 += 64) {
        __syncthreads();
#pragma unroll
        for (int i = 0; i < 4; ++i) {
            int chunk = i * 256 + wv * 64 + lane;
            int row   = chunk >> 3;
            int gph   = chunk & 7;
            int gda   = gph ^ (row & 7);
            gload_lds16(A  + (size_t)(m0 + row) * 2048 + kbase + k0 + gda * 8,
                        As + (i * 256 + wv * 64) * 8);
            gload_lds16(WT + (size_t)(n0 + row) * 2048 + kbase + k0 + gda * 8,
                        Bs + (i * 256 + wv * 64) * 8);
        }
        __syncthreads();
#pragma unroll
        for (int kk = 0; kk < 64; kk += 32) {
            short8 af[4], bfr[4];
#pragma unroll
            for (int i2 = 0; i2 < 4; ++i2) {
                int ra = wm + i2 * 16 + lm;
                int ga = ((kk >> 3) + lq) ^ (ra & 7);
                af[i2] = *(const short8*)(As + ra * 64 + ga * 8);
                int rb = wn + i2 * 16 + lm;
                int gb = ((kk >> 3) + lq) ^ (rb & 7);
                bfr[i2] = *(const short8*)(Bs + rb * 64 + gb * 8);
            }
#pragma unroll
            for (int mi = 0; mi < 4; ++mi)
#pragma unroll
                for (int ni = 0; ni < 4; ++ni)
                    acc[mi][ni] = __builtin_amdgcn_mfma_f32_16x16x32_bf16(
                        af[mi], bfr[ni], acc[mi][ni], 0, 0, 0);
        }
    }
    bf16* Gs = Gp + (size_t)s * GP_SSTR;
    const bool full = (s >= 4);               // s>=4: all cols < 512, always stored
#pragma unroll
    for (int mi = 0; mi < 4; ++mi)
#pragma unroll
        for (int ni = 0; ni < 4; ++ni) {
            int row = m0 + wm + mi * 16 + lq * 4;
            int col = n0 + wn + ni * 16 + lm;
            if (full || col < 672) {
#pragma unroll
                for (int r = 0; r < 4; ++r)
                    Gs[(size_t)(row + r) * NCOMB + col] = __float2bfloat16(acc[mi][ni][r]);
            }
        }
}

// ---------------------------------------------------------------------------
// combine: 1024 blocks x 128 thr; block bg handles b0=bg*2, b0+1 -> 16 rows r = bi*8+n.
__global__ __launch_bounds__(128) void combine(const bf16* __restrict__ Gp,
                                               const float* __restrict__ z,
                                               const bf16* __restrict__ WzT,
                                               const bf16* __restrict__ W2T,
                                               const float* __restrict__ bep1,
                                               const float* __restrict__ bep2,
                                               const float* __restrict__ bp1,
                                               const float* __restrict__ Wp2,
                                               const float* __restrict__ bp2,
                                               const float* __restrict__ Wp3,
                                               const float* __restrict__ bp3,
                                               float* __restrict__ out) {
    __shared__ float zf[512];          // [r=16][k=32]
    __shared__ short zbf[512];         // [r][k] bf16 A-frag layout
    __shared__ float hxs[1024];        // [bi=2][c=512] 8-slice sum + bep1
    __shared__ float h1s[320];         // [bi][160]
    __shared__ float h2s[320];
    __shared__ float ps[64];           // [bi][32]
    __shared__ short hB[16 * 512];     // [r][c] bf16, XOR-swizzled (layer-2 A-frags)
    __shared__ float o2s[512];         // [r][j]
    const int t = threadIdx.x, bg = blockIdx.x;
    const int b0 = bg * 2;
    const int lane = t & 63;
    const int jt = t >> 6;             // wave id: col-half for zW, n-tile for layer-2
    const int lm = lane & 15, lq = lane >> 4;

    // ---- phase 0: z, hx 8-slice sums, prior h1 (4 slices) ----
    {
        float4 v = *(const float4*)(z + (size_t)b0 * 256 + t * 4);
        zf[t * 4 + 0] = v.x; zf[t * 4 + 1] = v.y; zf[t * 4 + 2] = v.z; zf[t * 4 + 3] = v.w;
        zbf[t * 4 + 0] = f2bf_bits(v.x); zbf[t * 4 + 1] = f2bf_bits(v.y);
        zbf[t * 4 + 2] = f2bf_bits(v.z); zbf[t * 4 + 3] = f2bf_bits(v.w);
    }
#pragma unroll
    for (int g = 0; g < 2; ++g) {
        int q = g * 128 + t;               // 256 quads: bi(2) x cq(128)
        int bi = q >> 7, cq = q & 127;
        const unsigned short* gp =
            (const unsigned short*)(Gp + (size_t)(b0 + bi) * NCOMB + cq * 4);
        float4 a4 = *(const float4*)(bep1 + cq * 4);
#pragma unroll
        for (int s = 0; s < 8; ++s) {
            ushort4 v = *(const ushort4*)(gp + (size_t)s * GP_SSTR);
            a4.x += bfu2f(v.x); a4.y += bfu2f(v.y);
            a4.z += bfu2f(v.z); a4.w += bfu2f(v.w);
        }
        *(float4*)(hxs + bi * 512 + cq * 4) = a4;
    }
    for (int e = t; e < 320; e += 128) {
        int bi = (e >= 160), c = e - bi * 160;
        const unsigned short* gp =
            (const unsigned short*)(Gp + (size_t)(b0 + bi) * NCOMB + 512 + c);
        float v = bp1[c] + bfu2f(gp[0]) + bfu2f(gp[GP_SSTR])
                + bfu2f(gp[2 * GP_SSTR]) + bfu2f(gp[3 * GP_SSTR]);
        h1s[e] = fmaxf(v, 0.f);
    }
    __syncthreads();
    for (int e = t; e < 320; e += 128) {
        int bi = (e >= 160), c = e - bi * 160;
        int en = c / 5, g5 = c - en * 5;
        float a = bp2[c];
#pragma unroll
        for (int h = 0; h < 5; ++h)
            a += h1s[bi * 160 + en * 5 + h] * Wp2[en * 25 + h * 5 + g5];
        h2s[e] = fmaxf(a, 0.f);
    }
    __syncthreads();
    if (t < 64) {
        int bi = t >> 5, j = t & 31;
        float a = bp3[j];
#pragma unroll
        for (int g = 0; g < 5; ++g)
            a += h2s[bi * 160 + j * 5 + g] * Wp3[j * 5 + g];
        ps[bi * 32 + j] = a;
    }
    // ---- zW: h[r][c] = relu(hx + z@Wz); wave jt covers cols [jt*256, jt*256+256) ----
    short8 afz = *(const short8*)(zbf + lm * 32 + lq * 8);
#pragma unroll
    for (int u = 0; u < 16; ++u) {
        int crow = jt * 256 + u * 16 + lm;           // output col in [0,512)
        short8 bfz = *(const short8*)(WzT + crow * 32 + lq * 8);
        f32x4 az = {};
        az = __builtin_amdgcn_mfma_f32_16x16x32_bf16(afz, bfz, az, 0, 0, 0);
        int cg = crow >> 3, cl = crow & 7;
#pragma unroll
        for (int r = 0; r < 4; ++r) {
            int row = lq * 4 + r;                    // 0..15
            float hv = fmaxf(hxs[(row >> 3) * 512 + crow] + az[r], 0.f);
            hB[row * 512 + (cg ^ row) * 8 + cl] = f2bf_bits(hv);
        }
    }
    __syncthreads();
    // ---- layer-2: o2 = h @ Wep2 (M=16, N=32 via 2 waves, K=512) ----
    f32x4 o2acc = {};
    {
        int jrow = jt * 16 + lm;
#pragma unroll
        for (int ks = 0; ks < 16; ++ks) {
            int dg = ks * 4 + lq;
            short8 a2 = *(const short8*)(hB + lm * 512 + (dg ^ lm) * 8);
            short8 b2 = *(const short8*)(W2T + jrow * 512 + dg * 8);
            o2acc = __builtin_amdgcn_mfma_f32_16x16x32_bf16(a2, b2, o2acc, 0, 0, 0);
        }
    }
#pragma unroll
    for (int r = 0; r < 4; ++r)
        o2s[(lq * 4 + r) * 32 + jt * 16 + lm] = o2acc[r];
    __syncthreads();
    // ---- epilogue: out[b,n] = sum_j (o2 + bep2 + p) * z ----
    {
        int r = t >> 3, jg = t & 7;
        float val = 0.f;
#pragma unroll
        for (int u = 0; u < 4; ++u) {
            int j = jg * 4 + u;
            val += (o2s[r * 32 + j] + bep2[j] + ps[(r >> 3) * 32 + j]) * zf[r * 32 + j];
        }
        val += __shfl_xor(val, 1, 64);
        val += __shfl_xor(val, 2, 64);
        val += __shfl_xor(val, 4, 64);
        if ((t & 7) == 0) out[(size_t)bg * 16 + r] = val;
    }
}

// ---------------------------------------------------------------------------
extern "C" void kernel_launch(void* const* d_in, const int* in_sizes, int n_in,
                              void* d_out, int out_size, void* d_ws, size_t ws_size,
                              hipStream_t stream) {
    const float* x    = (const float*)d_in[0];
    const float* feat = (const float*)d_in[1];
    const float* z    = (const float*)d_in[2];
    const float* Wep1 = (const float*)d_in[3];
    const float* bep1 = (const float*)d_in[4];
    const float* Wep2 = (const float*)d_in[5];
    const float* bep2 = (const float*)d_in[6];
    const float* Wp1  = (const float*)d_in[7];
    const float* bp1  = (const float*)d_in[8];
    const float* Wp2  = (const float*)d_in[9];
    const float* bp2  = (const float*)d_in[10];
    const float* Wp3  = (const float*)d_in[11];
    const float* bp3  = (const float*)d_in[12];
    float* out = (float*)d_out;

    char* ws  = (char*)d_ws;
    bf16* A   = (bf16*)ws;
    bf16* WT  = (bf16*)(ws + A_BYTES);
    bf16* WzT = (bf16*)(ws + A_BYTES + WT_BYTES);
    bf16* W2T = (bf16*)(ws + A_BYTES + WT_BYTES + WZT_BYTES);
    bf16* Gp  = (bf16*)(ws + A_BYTES + WT_BYTES + WZT_BYTES + W2T_BYTES);  // [8][2048][768] bf16

    prep<<<5440, 256, 0, stream>>>(x, feat, Wep1, Wep2, Wp1, A, WT, WzT, W2T);
    gemm_split<<<dim3(16, 40), 256, 0, stream>>>(A, WT, Gp);
    combine<<<1024, 128, 0, stream>>>(Gp, z, WzT, W2T, bep1, bep2,
                                      bp1, Wp2, bp2, Wp3, bp3, out);
}

// Round 6
// 115.346 us; speedup vs baseline: 1.0176x; 1.0176x over previous
//
#include <hip/hip_runtime.h>
#include <hip/hip_bf16.h>

// EpiLinear: epinet (2080->512->32, z-contract) + prior ensemble (32x [1024->5->5->1], z-contract)
// B=2048, NZ=8, ND=32, STATE=HIDDEN=1024, EPI_HIDDEN=512. All inputs/outputs FP32.
//
//  - hx = [x|feature] @ Wep1[0:2048,:] shared across 8 z-samples -> GEMM [2048x2048]x[2048x672]
//    (prior layer-1 folded in as cols 512..671 of WT).
//  - GEMM (this round): 64x128 (MxN) tile, split-K=8 -> 32x40 = 1280 blocks = 5.0/CU uniform
//    (round-5 lesson: 640 blocks @2.5/CU had the same makespan as 768 @3/CU; makespan, not
//    FLOPs, is what counts). mfma 16x16x32 bf16, global_load_lds w=16, XOR LDS swizzle,
//    24KB LDS/block. Slices 0-3 (k<1024) cover cols 0..767, slices 4-7 cols 0..511.
//  - Gp partials bf16 (error ~0.003 << 0.82 threshold).
//  - combine: 1024 blocks x 128 thr, 2 b's/block (16 rows = one M=16 MFMA tile); zW + layer-2
//    via MFMA, B-frags straight from global WzT/W2T (L2-resident); prior tail fp32 VALU.

typedef __hip_bfloat16 bf16;
typedef __attribute__((ext_vector_type(8))) short short8;   // 8 bf16 = 4 VGPRs (MFMA A/B frag)
typedef __attribute__((ext_vector_type(4))) float f32x4;    // MFMA C/D frag

#define NCOMB 768
#define A_BYTES   (2048u * 2048u * 2u)
#define WT_BYTES  (768u * 2048u * 2u)
#define WZT_BYTES (512u * 32u * 2u)
#define W2T_BYTES (32u * 512u * 2u)
#define GP_SSTR ((size_t)2048 * NCOMB)

__device__ __forceinline__ void gload_lds16(const bf16* g, bf16* l) {
    __builtin_amdgcn_global_load_lds(
        (const __attribute__((address_space(1))) void*)g,
        (__attribute__((address_space(3))) void*)l, 16, 0, 0);
}

__device__ __forceinline__ short f2bf_bits(float f) {
    bf16 h = __float2bfloat16(f);
    return *reinterpret_cast<short*>(&h);
}
__device__ __forceinline__ float bfu2f(unsigned short u) {
    return __uint_as_float(((unsigned int)u) << 16);
}

// ---------------------------------------------------------------------------
// merged prep: [0,4096) A; [4096,4352) WT transpose; [4352,5376) WT prior (k<1024 only);
//              [5376,5408) WzT; [5408,5440) W2T.
__global__ __launch_bounds__(256) void prep(const float* __restrict__ x,
                                            const float* __restrict__ feat,
                                            const float* __restrict__ Wep1,
                                            const float* __restrict__ Wep2,
                                            const float* __restrict__ Wp1,
                                            bf16* __restrict__ A,
                                            bf16* __restrict__ WT,
                                            bf16* __restrict__ WzT,
                                            bf16* __restrict__ W2T) {
    const int t = threadIdx.x;
    const int blk = blockIdx.x;
    if (blk < 4096) {
        // A[b][0:1024]=x[b], A[b][1024:2048]=feature[b]
        int idx = blk * 256 + t;
        int b = idx >> 9;
        int g = idx & 511;
        const float* src = (g < 256) ? (x + (size_t)b * 1024 + g * 4)
                                     : (feat + (size_t)b * 1024 + (g - 256) * 4);
        float4 v = *(const float4*)src;
        short4 p;
        p.x = f2bf_bits(v.x); p.y = f2bf_bits(v.y);
        p.z = f2bf_bits(v.z); p.w = f2bf_bits(v.w);
        *(short4*)(A + (size_t)b * 2048 + g * 4) = p;
    } else if (blk < 4352) {
        // 64x64 tiled transpose of Wep1[0:2048][0:512] -> WT[n][k]
        __shared__ short tile[64 * 66];
        int wb = blk - 4096;
        int kt = wb >> 3, nt = wb & 7;
        int k0 = kt * 64, n0 = nt * 64;
        int r = t >> 4, cq = t & 15;
#pragma unroll
        for (int i = 0; i < 4; ++i) {
            int rr = r + i * 16;
            float4 v = *(const float4*)(Wep1 + (size_t)(k0 + rr) * 512 + n0 + cq * 4);
            tile[(cq * 4 + 0) * 66 + rr] = f2bf_bits(v.x);
            tile[(cq * 4 + 1) * 66 + rr] = f2bf_bits(v.y);
            tile[(cq * 4 + 2) * 66 + rr] = f2bf_bits(v.z);
            tile[(cq * 4 + 3) * 66 + rr] = f2bf_bits(v.w);
        }
        __syncthreads();
#pragma unroll
        for (int i = 0; i < 2; ++i) {
            int ch = i * 256 + t;
            int nr = ch >> 3, kc = ch & 7;
            short8 s = *(const short8*)(tile + nr * 66 + kc * 8);
            *(short8*)(WT + (size_t)(n0 + nr) * 2048 + k0 + kc * 8) = s;
        }
    } else if (blk < 5376) {
        // prior cols 512..767, k<1024 only (k>=1024 never read: slices 4-7 stop at col 512)
        int local = (blk - 4352) * 256 + t;       // 262144: n in [512,768) x k in [0,1024)
        int n = 512 + (local >> 10);
        int k = local & 1023;
        float v = 0.f;
        if (n < 672) {
            int q = n - 512;
            int e = q / 5, h = q - e * 5;
            v = Wp1[(size_t)e * 5120 + k * 5 + h];
        }
        WT[(size_t)n * 2048 + k] = __float2bfloat16(v);
    } else if (blk < 5408) {
        // WzT[c][k] = Wep1[2048+k][c]
        int local = (blk - 5376) * 256 + t;
#pragma unroll
        for (int i = 0; i < 2; ++i) {
            int e = i * 8192 + local;
            int c = e >> 5, k = e & 31;
            WzT[e] = __float2bfloat16(Wep1[(size_t)(2048 + k) * 512 + c]);
        }
    } else {
        // W2T[j][c] = Wep2[c][j]
        int local = (blk - 5408) * 256 + t;
#pragma unroll
        for (int i = 0; i < 2; ++i) {
            int e = i * 8192 + local;
            int j = e >> 9, c = e & 511;
            W2T[e] = __float2bfloat16(Wep2[(size_t)c * 32 + j]);
        }
    }
}

// ---------------------------------------------------------------------------
// Gp[s][b][c] (bf16) = sum_{k in [s*256,(s+1)*256)} A[b][k] * WT[c][k].
// 64x128 tile. grid (32, 40): y<24 -> s=y/6, ny=y%6; y>=24 -> s=4+(y-24)/4, ny=(y-24)%4.
// 1280 blocks = 5.0/CU uniform. x = m-tile: same-A-stripe blocks (stride 32) share an XCD.
__global__ __launch_bounds__(256) void gemm_split(const bf16* __restrict__ A,
                                                  const bf16* __restrict__ WT,
                                                  bf16* __restrict__ Gp) {
    __shared__ bf16 As[64 * 64];
    __shared__ bf16 Bs[128 * 64];
    const int t    = threadIdx.x;
    const int lane = t & 63;
    const int wv   = t >> 6;
    const int y = blockIdx.y;
    int s, ny;
    if (y < 24) { s = y / 6; ny = y - s * 6; }
    else        { int q = y - 24; s = 4 + (q >> 2); ny = q & 3; }
    const int m0 = blockIdx.x * 64;
    const int n0 = ny * 128;
    const int kbase = s * 256;
    const int lm = lane & 15;
    const int lq = lane >> 4;
    const int wm = (wv & 1) * 32;             // wave m-offset (2x 32-row halves)
    const int wn = (wv >> 1) * 64;            // wave n-offset (2x 64-col halves)
    f32x4 acc[2][4] = {};

    for (int k0 = 0; k0 < 256; k0 += 64) {
        __syncthreads();
#pragma unroll
        for (int i = 0; i < 2; ++i) {          // A: 512 chunks of 16B
            int chunk = i * 256 + wv * 64 + lane;
            int row   = chunk >> 3;
            int gph   = chunk & 7;
            int gda   = gph ^ (row & 7);
            gload_lds16(A  + (size_t)(m0 + row) * 2048 + kbase + k0 + gda * 8,
                        As + (i * 256 + wv * 64) * 8);
        }
#pragma unroll
        for (int i = 0; i < 4; ++i) {          // B: 1024 chunks of 16B
            int chunk = i * 256 + wv * 64 + lane;
            int row   = chunk >> 3;
            int gph   = chunk & 7;
            int gda   = gph ^ (row & 7);
            gload_lds16(WT + (size_t)(n0 + row) * 2048 + kbase + k0 + gda * 8,
                        Bs + (i * 256 + wv * 64) * 8);
        }
        __syncthreads();
#pragma unroll
        for (int kk = 0; kk < 64; kk += 32) {
            short8 af[2], bfr[4];
#pragma unroll
            for (int i2 = 0; i2 < 2; ++i2) {
                int ra = wm + i2 * 16 + lm;
                int ga = ((kk >> 3) + lq) ^ (ra & 7);
                af[i2] = *(const short8*)(As + ra * 64 + ga * 8);
            }
#pragma unroll
            for (int i2 = 0; i2 < 4; ++i2) {
                int rb = wn + i2 * 16 + lm;
                int gb = ((kk >> 3) + lq) ^ (rb & 7);
                bfr[i2] = *(const short8*)(Bs + rb * 64 + gb * 8);
            }
#pragma unroll
            for (int mi = 0; mi < 2; ++mi)
#pragma unroll
                for (int ni = 0; ni < 4; ++ni)
                    acc[mi][ni] = __builtin_amdgcn_mfma_f32_16x16x32_bf16(
                        af[mi], bfr[ni], acc[mi][ni], 0, 0, 0);
        }
    }
    bf16* Gs = Gp + (size_t)s * GP_SSTR;
    const bool full = (s >= 4);               // s>=4: all cols < 512, always stored
#pragma unroll
    for (int mi = 0; mi < 2; ++mi)
#pragma unroll
        for (int ni = 0; ni < 4; ++ni) {
            int row = m0 + wm + mi * 16 + lq * 4;
            int col = n0 + wn + ni * 16 + lm;
            if (full || col < 672) {
#pragma unroll
                for (int r = 0; r < 4; ++r)
                    Gs[(size_t)(row + r) * NCOMB + col] = __float2bfloat16(acc[mi][ni][r]);
            }
        }
}

// ---------------------------------------------------------------------------
// combine: 1024 blocks x 128 thr; block bg handles b0=bg*2, b0+1 -> 16 rows r = bi*8+n.
__global__ __launch_bounds__(128) void combine(const bf16* __restrict__ Gp,
                                               const float* __restrict__ z,
                                               const bf16* __restrict__ WzT,
                                               const bf16* __restrict__ W2T,
                                               const float* __restrict__ bep1,
                                               const float* __restrict__ bep2,
                                               const float* __restrict__ bp1,
                                               const float* __restrict__ Wp2,
                                               const float* __restrict__ bp2,
                                               const float* __restrict__ Wp3,
                                               const float* __restrict__ bp3,
                                               float* __restrict__ out) {
    __shared__ float zf[512];          // [r=16][k=32]
    __shared__ short zbf[512];         // [r][k] bf16 A-frag layout
    __shared__ float hxs[1024];        // [bi=2][c=512] 8-slice sum + bep1
    __shared__ float h1s[320];         // [bi][160]
    __shared__ float h2s[320];
    __shared__ float ps[64];           // [bi][32]
    __shared__ short hB[16 * 512];     // [r][c] bf16, XOR-swizzled (layer-2 A-frags)
    __shared__ float o2s[512];         // [r][j]
    const int t = threadIdx.x, bg = blockIdx.x;
    const int b0 = bg * 2;
    const int lane = t & 63;
    const int jt = t >> 6;             // wave id: col-half for zW, n-tile for layer-2
    const int lm = lane & 15, lq = lane >> 4;

    // ---- phase 0: z, hx 8-slice sums, prior h1 (4 slices) ----
    {
        float4 v = *(const float4*)(z + (size_t)b0 * 256 + t * 4);
        zf[t * 4 + 0] = v.x; zf[t * 4 + 1] = v.y; zf[t * 4 + 2] = v.z; zf[t * 4 + 3] = v.w;
        zbf[t * 4 + 0] = f2bf_bits(v.x); zbf[t * 4 + 1] = f2bf_bits(v.y);
        zbf[t * 4 + 2] = f2bf_bits(v.z); zbf[t * 4 + 3] = f2bf_bits(v.w);
    }
#pragma unroll
    for (int g = 0; g < 2; ++g) {
        int q = g * 128 + t;               // 256 quads: bi(2) x cq(128)
        int bi = q >> 7, cq = q & 127;
        const unsigned short* gp =
            (const unsigned short*)(Gp + (size_t)(b0 + bi) * NCOMB + cq * 4);
        float4 a4 = *(const float4*)(bep1 + cq * 4);
#pragma unroll
        for (int s = 0; s < 8; ++s) {
            ushort4 v = *(const ushort4*)(gp + (size_t)s * GP_SSTR);
            a4.x += bfu2f(v.x); a4.y += bfu2f(v.y);
            a4.z += bfu2f(v.z); a4.w += bfu2f(v.w);
        }
        *(float4*)(hxs + bi * 512 + cq * 4) = a4;
    }
    for (int e = t; e < 320; e += 128) {
        int bi = (e >= 160), c = e - bi * 160;
        const unsigned short* gp =
            (const unsigned short*)(Gp + (size_t)(b0 + bi) * NCOMB + 512 + c);
        float v = bp1[c] + bfu2f(gp[0]) + bfu2f(gp[GP_SSTR])
                + bfu2f(gp[2 * GP_SSTR]) + bfu2f(gp[3 * GP_SSTR]);
        h1s[e] = fmaxf(v, 0.f);
    }
    __syncthreads();
    for (int e = t; e < 320; e += 128) {
        int bi = (e >= 160), c = e - bi * 160;
        int en = c / 5, g5 = c - en * 5;
        float a = bp2[c];
#pragma unroll
        for (int h = 0; h < 5; ++h)
            a += h1s[bi * 160 + en * 5 + h] * Wp2[en * 25 + h * 5 + g5];
        h2s[e] = fmaxf(a, 0.f);
    }
    __syncthreads();
    if (t < 64) {
        int bi = t >> 5, j = t & 31;
        float a = bp3[j];
#pragma unroll
        for (int g = 0; g < 5; ++g)
            a += h2s[bi * 160 + j * 5 + g] * Wp3[j * 5 + g];
        ps[bi * 32 + j] = a;
    }
    // ---- zW: h[r][c] = relu(hx + z@Wz); wave jt covers cols [jt*256, jt*256+256) ----
    short8 afz = *(const short8*)(zbf + lm * 32 + lq * 8);
#pragma unroll
    for (int u = 0; u < 16; ++u) {
        int crow = jt * 256 + u * 16 + lm;           // output col in [0,512)
        short8 bfz = *(const short8*)(WzT + crow * 32 + lq * 8);
        f32x4 az = {};
        az = __builtin_amdgcn_mfma_f32_16x16x32_bf16(afz, bfz, az, 0, 0, 0);
        int cg = crow >> 3, cl = crow & 7;
#pragma unroll
        for (int r = 0; r < 4; ++r) {
            int row = lq * 4 + r;                    // 0..15
            float hv = fmaxf(hxs[(row >> 3) * 512 + crow] + az[r], 0.f);
            hB[row * 512 + (cg ^ row) * 8 + cl] = f2bf_bits(hv);
        }
    }
    __syncthreads();
    // ---- layer-2: o2 = h @ Wep2 (M=16, N=32 via 2 waves, K=512) ----
    f32x4 o2acc = {};
    {
        int jrow = jt * 16 + lm;
#pragma unroll
        for (int ks = 0; ks < 16; ++ks) {
            int dg = ks * 4 + lq;
            short8 a2 = *(const short8*)(hB + lm * 512 + (dg ^ lm) * 8);
            short8 b2 = *(const short8*)(W2T + jrow * 512 + dg * 8);
            o2acc = __builtin_amdgcn_mfma_f32_16x16x32_bf16(a2, b2, o2acc, 0, 0, 0);
        }
    }
#pragma unroll
    for (int r = 0; r < 4; ++r)
        o2s[(lq * 4 + r) * 32 + jt * 16 + lm] = o2acc[r];
    __syncthreads();
    // ---- epilogue: out[b,n] = sum_j (o2 + bep2 + p) * z ----
    {
        int r = t >> 3, jg = t & 7;
        float val = 0.f;
#pragma unroll
        for (int u = 0; u < 4; ++u) {
            int j = jg * 4 + u;
            val += (o2s[r * 32 + j] + bep2[j] + ps[(r >> 3) * 32 + j]) * zf[r * 32 + j];
        }
        val += __shfl_xor(val, 1, 64);
        val += __shfl_xor(val, 2, 64);
        val += __shfl_xor(val, 4, 64);
        if ((t & 7) == 0) out[(size_t)bg * 16 + r] = val;
    }
}

// ---------------------------------------------------------------------------
extern "C" void kernel_launch(void* const* d_in, const int* in_sizes, int n_in,
                              void* d_out, int out_size, void* d_ws, size_t ws_size,
                              hipStream_t stream) {
    const float* x    = (const float*)d_in[0];
    const float* feat = (const float*)d_in[1];
    const float* z    = (const float*)d_in[2];
    const float* Wep1 = (const float*)d_in[3];
    const float* bep1 = (const float*)d_in[4];
    const float* Wep2 = (const float*)d_in[5];
    const float* bep2 = (const float*)d_in[6];
    const float* Wp1  = (const float*)d_in[7];
    const float* bp1  = (const float*)d_in[8];
    const float* Wp2  = (const float*)d_in[9];
    const float* bp2  = (const float*)d_in[10];
    const float* Wp3  = (const float*)d_in[11];
    const float* bp3  = (const float*)d_in[12];
    float* out = (float*)d_out;

    char* ws  = (char*)d_ws;
    bf16* A   = (bf16*)ws;
    bf16* WT  = (bf16*)(ws + A_BYTES);
    bf16* WzT = (bf16*)(ws + A_BYTES + WT_BYTES);
    bf16* W2T = (bf16*)(ws + A_BYTES + WT_BYTES + WZT_BYTES);
    bf16* Gp  = (bf16*)(ws + A_BYTES + WT_BYTES + WZT_BYTES + W2T_BYTES);  // [8][2048][768] bf16

    prep<<<5440, 256, 0, stream>>>(x, feat, Wep1, Wep2, Wp1, A, WT, WzT, W2T);
    gemm_split<<<dim3(32, 40), 256, 0, stream>>>(A, WT, Gp);
    combine<<<1024, 128, 0, stream>>>(Gp, z, WzT, W2T, bep1, bep2,
                                      bp1, Wp2, bp2, Wp3, bp3, out);
}